// Round 1
// baseline (985.399 us; speedup 1.0000x reference)
//
#include <hip/hip_runtime.h>
#include <hip/hip_bf16.h>

// Problem constants
#define DM     128
#define DSTATE 16
#define DINNER 256
#define CCONV  16
#define NEIGH  27
#define DSEQ   432   // CCONV * NEIGH
#define DTRANK 14
#define LVOL   4096  // 16*16*16
#define BATCH  2
#define NTOK   8192  // BATCH * LVOL

// ---------------------------------------------------------------- transposes
__global__ void k_transpose(const float* __restrict__ src, float* __restrict__ dst,
                            int rows, int cols) {
    int i = blockIdx.x * 256 + threadIdx.x;
    if (i < rows * cols) {
        int r = i / cols, c = i - r * cols;
        dst[c * rows + r] = src[i];
    }
}

// ---------------------------------------------------------------- in-proj GEMM
// xz[tok, 0:256] = xp, xz[tok, 256:512] = z.  16 tokens per block.
__global__ void k_inproj(const float* __restrict__ x, const float* __restrict__ w_in_t,
                         float* __restrict__ xz) {
    int t = threadIdx.x;
    int tokbase = blockIdx.x * 16;
    __shared__ float xs_[16][128];
    for (int idx = t; idx < 2048; idx += 256)
        xs_[idx >> 7][idx & 127] = x[tokbase * 128 + idx];
    __syncthreads();
    float a0[16], a1[16];
#pragma unroll
    for (int k = 0; k < 16; k++) { a0[k] = 0.f; a1[k] = 0.f; }
    for (int j = 0; j < 128; j++) {
        float w0 = w_in_t[j * 512 + t];
        float w1 = w_in_t[j * 512 + t + 256];
#pragma unroll
        for (int k = 0; k < 16; k++) {
            float xv = xs_[k][j];
            a0[k] += xv * w0;
            a1[k] += xv * w1;
        }
    }
#pragma unroll
    for (int k = 0; k < 16; k++) {
        xz[(tokbase + k) * 512 + t]       = a0[k];
        xz[(tokbase + k) * 512 + t + 256] = a1[k];
    }
}

// ---------------------------------------------------------------- grouped conv3d + SiLU
// xc channel-major: xc[(b*16+co)*4096 + l]
__global__ void k_conv(const float* __restrict__ xz, const float* __restrict__ conv_w,
                       const float* __restrict__ conv_b, float* __restrict__ xc) {
    int t = threadIdx.x;
    int tok = blockIdx.x * 256 + t;
    int co = blockIdx.y;
    int b = tok >> 12, l = tok & 4095;
    int d = l >> 8, h = (l >> 4) & 15, w = l & 15;
    float acc = conv_b[co];
    const float* wr = conv_w + co * 16 * 27;
    for (int i = 0; i < 3; i++) {
        int zd = d + i - 1; if ((unsigned)zd > 15u) continue;
        for (int j = 0; j < 3; j++) {
            int zh = h + j - 1; if ((unsigned)zh > 15u) continue;
            for (int k = 0; k < 3; k++) {
                int zw = w + k - 1; if ((unsigned)zw > 15u) continue;
                int ntok = (b << 12) + (zd << 8) + (zh << 4) + zw;
                const float* xr = xz + ntok * 512 + co * 16;
                int widx = (i * 3 + j) * 3 + k;
#pragma unroll
                for (int q = 0; q < 16; q++)
                    acc += xr[q] * wr[q * 27 + widx];
            }
        }
    }
    acc = acc / (1.f + __expf(-acc));  // SiLU
    xc[(b * 16 + co) * 4096 + l] = acc;
}

// ---------------------------------------------------------------- x_dbl = x_proj_w @ xs
// xs gathered from xc on the fly (unfold). 6 output channels per block (grid.y=8).
__global__ void k_xdbl(const float* __restrict__ xc, const float* __restrict__ x_proj_w,
                       float* __restrict__ x_dbl) {
    int t = threadIdx.x;
    int tok = blockIdx.x * 256 + t;
    int cbase = blockIdx.y * 6;
    int ncs = (cbase + 6 <= 46) ? 6 : (46 - cbase);
    int b = tok >> 12, l = tok & 4095;
    int d0 = l >> 8, h0 = (l >> 4) & 15, w0 = l & 15;
    int nbo[27];
#pragma unroll
    for (int t27 = 0; t27 < 27; t27++) {
        int di = t27 / 9 - 1, dj = (t27 / 3) % 3 - 1, dk = t27 % 3 - 1;
        int zd = d0 + di, zh = h0 + dj, zw = w0 + dk;
        nbo[t27] = ((unsigned)zd > 15u || (unsigned)zh > 15u || (unsigned)zw > 15u)
                   ? -1 : ((zd << 8) + (zh << 4) + zw);
    }
    const float* xcb = xc + b * 16 * 4096;
    float acc[6];
#pragma unroll
    for (int c = 0; c < 6; c++) acc[c] = 0.f;
    for (int ch = 0; ch < 16; ch++) {
        const float* xr = xcb + ch * 4096;
#pragma unroll
        for (int t27 = 0; t27 < 27; t27++) {
            int o = nbo[t27];
            float v = (o >= 0) ? xr[o] : 0.f;
            int didx = ch * 27 + t27;
#pragma unroll
            for (int c = 0; c < 6; c++) {
                if (c < ncs)
                    acc[c] += v * x_proj_w[(cbase + c) * 432 + didx];
            }
        }
    }
    for (int c = 0; c < ncs; c++)
        x_dbl[(b * 46 + cbase + c) * 4096 + l] = acc[c];
}

// ---------------------------------------------------------------- delta = softplus(dt_w @ dts + dt_b)
// 16 dd-channels per block (grid.y = 27)
__global__ void k_delta(const float* __restrict__ x_dbl, const float* __restrict__ dt_w,
                        const float* __restrict__ dt_b, float* __restrict__ delta) {
    int t = threadIdx.x;
    int tok = blockIdx.x * 256 + t;
    int ddbase = blockIdx.y * 16;
    int b = tok >> 12, l = tok & 4095;
    const float* xr = x_dbl + b * 46 * 4096;
    float xv[14];
#pragma unroll
    for (int r = 0; r < 14; r++) xv[r] = xr[r * 4096 + l];
#pragma unroll
    for (int dd2 = 0; dd2 < 16; dd2++) {
        int dd = ddbase + dd2;
        float s = dt_b[dd];
#pragma unroll
        for (int r = 0; r < 14; r++) s += xv[r] * dt_w[dd * 14 + r];
        s = (s > 15.f) ? s : log1pf(__expf(s));
        delta[(b * 432 + dd) * 4096 + l] = s;
    }
}

// ---------------------------------------------------------------- selective scan
// One block per (b, d-channel). 16 l-chunks x 16 states; 2-pass chunked scan.
__global__ void k_scan(const float* __restrict__ xc, const float* __restrict__ delta,
                       const float* __restrict__ x_dbl, const float* __restrict__ A_logs,
                       const float* __restrict__ Ds, float* __restrict__ y) {
    int bd = blockIdx.x;
    int b = bd / 432, dch = bd % 432;
    int c = threadIdx.x >> 4, n = threadIdx.x & 15;

    float Aa = -__expf(A_logs[dch * 16 + n]);
    float Dskip = Ds[dch];
    int cch = dch / 27, t27 = dch % 27;
    int di = t27 / 9 - 1, dj = (t27 / 3) % 3 - 1, dk = t27 % 3 - 1;
    const float* xcb = xc + (b * 16 + cch) * 4096;
    const float* dl  = delta + (b * 432 + dch) * 4096;
    const float* Bmr = x_dbl + (b * 46 + 14 + n) * 4096;
    const float* Cmr = x_dbl + (b * 46 + 30 + n) * 4096;

    int l0 = c * 256;
    // pass 1: per-chunk aggregate (Ap, Bp)
    float Ap = 1.f, Bp = 0.f;
    for (int i = 0; i < 256; i++) {
        int l = l0 + i;
        int zd = (l >> 8) + di, zh = ((l >> 4) & 15) + dj, zw = (l & 15) + dk;
        float u = 0.f;
        if (!((unsigned)zd > 15u || (unsigned)zh > 15u || (unsigned)zw > 15u))
            u = xcb[(zd << 8) + (zh << 4) + zw];
        float dt = dl[l];
        float a = __expf(dt * Aa);
        float bv = dt * u * Bmr[l];
        Ap *= a;
        Bp = a * Bp + bv;
    }
    __shared__ float sA[16][16], sB[16][16];
    sA[c][n] = Ap; sB[c][n] = Bp;
    __syncthreads();
    if (threadIdx.x < 16) {  // serial exclusive prefix over 16 chunks for state nn
        int nn = threadIdx.x;
        float accA = 1.f, accB = 0.f;
        for (int cc = 0; cc < 16; cc++) {
            float ta = sA[cc][nn], tb = sB[cc][nn];
            sA[cc][nn] = accA; sB[cc][nn] = accB;
            accB = ta * accB + tb;
            accA *= ta;
        }
    }
    __syncthreads();
    float h = sB[c][n];  // incoming state (h_{-1}=0)
    for (int i = 0; i < 256; i++) {
        int l = l0 + i;
        int zd = (l >> 8) + di, zh = ((l >> 4) & 15) + dj, zw = (l & 15) + dk;
        float u = 0.f;
        if (!((unsigned)zd > 15u || (unsigned)zh > 15u || (unsigned)zw > 15u))
            u = xcb[(zd << 8) + (zh << 4) + zw];
        float dt = dl[l];
        float a = __expf(dt * Aa);
        float bv = dt * u * Bmr[l];
        h = a * h + bv;
        float p = h * Cmr[l];
        p += __shfl_xor(p, 1, 64);
        p += __shfl_xor(p, 2, 64);
        p += __shfl_xor(p, 4, 64);
        p += __shfl_xor(p, 8, 64);
        if (n == 0)
            y[(b * 432 + dch) * 4096 + l] = p + Dskip * u;
    }
}

// ---------------------------------------------------------------- fold GEMM + LN + gate + out GEMM
// 16 tokens per block.
__global__ void k_tail(const float* __restrict__ y, const float* __restrict__ xz,
                       const float* __restrict__ wf_t, const float* __restrict__ ln_g,
                       const float* __restrict__ ln_b, const float* __restrict__ wo_t,
                       float* __restrict__ out) {
    int t = threadIdx.x;
    int tokbase = blockIdx.x * 16;
    int b = tokbase >> 12, lbase = tokbase & 4095;
    __shared__ float ys[432][16];
    __shared__ float vs[256][17];
    __shared__ float mu_s[16], rs_s[16];

    for (int idx = t; idx < 432 * 16; idx += 256) {
        int d = idx >> 4, tk = idx & 15;
        ys[d][tk] = y[(b * 432 + d) * 4096 + lbase + tk];
    }
    __syncthreads();

    float acc[16];
#pragma unroll
    for (int k = 0; k < 16; k++) acc[k] = 0.f;
    for (int d = 0; d < 432; d++) {
        float w = wf_t[d * 256 + t];
#pragma unroll
        for (int k = 0; k < 16; k++) acc[k] += w * ys[d][k];
    }
    // stash for LN reduction
#pragma unroll
    for (int k = 0; k < 16; k++) vs[t][k] = acc[k];
    __syncthreads();

    {   // token tk = t>>4, 16 threads (sub = t&15) reduce 256 entries
        int tk = t >> 4, sub = t & 15;
        float s = 0.f, s2 = 0.f;
        for (int m = 0; m < 16; m++) {
            float v = vs[sub * 16 + m][tk];
            s += v; s2 += v * v;
        }
        s  += __shfl_xor(s, 1, 64);  s2 += __shfl_xor(s2, 1, 64);
        s  += __shfl_xor(s, 2, 64);  s2 += __shfl_xor(s2, 2, 64);
        s  += __shfl_xor(s, 4, 64);  s2 += __shfl_xor(s2, 4, 64);
        s  += __shfl_xor(s, 8, 64);  s2 += __shfl_xor(s2, 8, 64);
        if (sub == 0) {
            float mu = s * (1.f / 256.f);
            float var = s2 * (1.f / 256.f) - mu * mu;
            mu_s[tk] = mu;
            rs_s[tk] = rsqrtf(var + 1e-5f);
        }
    }
    __syncthreads();

    float g = ln_g[t], be = ln_b[t];
#pragma unroll
    for (int k = 0; k < 16; k++) {
        float zv = xz[(tokbase + k) * 512 + 256 + t];
        float sz = zv / (1.f + __expf(-zv));  // SiLU(z)
        vs[t][k] = ((acc[k] - mu_s[k]) * rs_s[k] * g + be) * sz;
    }
    __syncthreads();

    // out GEMM: 128 outputs x 16 tokens; each thread: 1 output x 8 tokens
    float oacc[8];
#pragma unroll
    for (int k = 0; k < 8; k++) oacc[k] = 0.f;
    int o = t & 127, kh = (t >> 7) * 8;
    for (int i = 0; i < 256; i++) {
        float w = wo_t[i * 128 + o];
#pragma unroll
        for (int k = 0; k < 8; k++) oacc[k] += w * vs[i][kh + k];
    }
#pragma unroll
    for (int k = 0; k < 8; k++)
        out[(tokbase + kh + k) * 128 + o] = oacc[k];
}

// ---------------------------------------------------------------- launch
extern "C" void kernel_launch(void* const* d_in, const int* in_sizes, int n_in,
                              void* d_out, int out_size, void* d_ws, size_t ws_size,
                              hipStream_t stream) {
    const float* x        = (const float*)d_in[0];
    const float* w_in     = (const float*)d_in[1];
    const float* conv_w   = (const float*)d_in[2];
    const float* conv_b   = (const float*)d_in[3];
    const float* x_proj_w = (const float*)d_in[4];
    const float* dt_w     = (const float*)d_in[5];
    const float* dt_b     = (const float*)d_in[6];
    const float* A_logs   = (const float*)d_in[7];
    const float* Ds       = (const float*)d_in[8];
    const float* w_fold   = (const float*)d_in[9];
    const float* ln_g     = (const float*)d_in[10];
    const float* ln_b     = (const float*)d_in[11];
    const float* w_out    = (const float*)d_in[12];
    float* out = (float*)d_out;

    float* ws    = (float*)d_ws;
    float* xz    = ws;                    // NTOK*512      = 4,194,304
    float* xc    = xz    + 4194304;       // B*16*L        =   131,072
    float* xdbl  = xc    + 131072;        // B*46*L        =   376,832
    float* delta = xdbl  + 376832;        // B*432*L       = 3,538,944
    float* ybuf  = delta + 3538944;       // B*432*L       = 3,538,944
    float* wint  = ybuf  + 3538944;       // 512*128       =    65,536
    float* wft   = wint  + 65536;         // 432*256       =   110,592
    float* wot   = wft   + 110592;        // 256*128       =    32,768

    // weight transposes
    k_transpose<<<dim3((512 * 128 + 255) / 256), dim3(256), 0, stream>>>(w_in, wint, 512, 128);
    k_transpose<<<dim3((256 * 432 + 255) / 256), dim3(256), 0, stream>>>(w_fold, wft, 256, 432);
    k_transpose<<<dim3((128 * 256 + 255) / 256), dim3(256), 0, stream>>>(w_out, wot, 128, 256);

    k_inproj<<<dim3(NTOK / 16), dim3(256), 0, stream>>>(x, wint, xz);
    k_conv<<<dim3(NTOK / 256, CCONV), dim3(256), 0, stream>>>(xz, conv_w, conv_b, xc);
    k_xdbl<<<dim3(NTOK / 256, 8), dim3(256), 0, stream>>>(xc, x_proj_w, xdbl);
    k_delta<<<dim3(NTOK / 256, 27), dim3(256), 0, stream>>>(xdbl, dt_w, dt_b, delta);
    k_scan<<<dim3(BATCH * DSEQ), dim3(256), 0, stream>>>(xc, delta, xdbl, A_logs, Ds, ybuf);
    k_tail<<<dim3(NTOK / 16), dim3(256), 0, stream>>>(ybuf, xz, wft, ln_g, ln_b, wot, out);
}

// Round 2
// 390.040 us; speedup vs baseline: 2.5264x; 2.5264x over previous
//
#include <hip/hip_runtime.h>
#include <hip/hip_bf16.h>

// Problem constants
#define DM     128
#define DSTATE 16
#define DINNER 256
#define CCONV  16
#define NEIGH  27
#define DSEQ   432   // CCONV * NEIGH
#define DTRANK 14
#define LVOL   4096  // 16*16*16
#define BATCH  2
#define NTOK   8192  // BATCH * LVOL

// ---------------------------------------------------------------- transposes
__global__ void k_transpose(const float* __restrict__ src, float* __restrict__ dst,
                            int rows, int cols) {
    int i = blockIdx.x * 256 + threadIdx.x;
    if (i < rows * cols) {
        int r = i / cols, c = i - r * cols;
        dst[c * rows + r] = src[i];
    }
}

// ---------------------------------------------------------------- in-proj GEMM
// xz[tok, 0:256] = xp, xz[tok, 256:512] = z.  16 tokens per block.
__global__ void k_inproj(const float* __restrict__ x, const float* __restrict__ w_in_t,
                         float* __restrict__ xz) {
    int t = threadIdx.x;
    int tokbase = blockIdx.x * 16;
    __shared__ float xs_[16][128];
    for (int idx = t; idx < 2048; idx += 256)
        xs_[idx >> 7][idx & 127] = x[tokbase * 128 + idx];
    __syncthreads();
    float a0[16], a1[16];
#pragma unroll
    for (int k = 0; k < 16; k++) { a0[k] = 0.f; a1[k] = 0.f; }
    for (int j = 0; j < 128; j++) {
        float w0 = w_in_t[j * 512 + t];
        float w1 = w_in_t[j * 512 + t + 256];
#pragma unroll
        for (int k = 0; k < 16; k++) {
            float xv = xs_[k][j];
            a0[k] += xv * w0;
            a1[k] += xv * w1;
        }
    }
#pragma unroll
    for (int k = 0; k < 16; k++) {
        xz[(tokbase + k) * 512 + t]       = a0[k];
        xz[(tokbase + k) * 512 + t + 256] = a1[k];
    }
}

// ---------------------------------------------------------------- grouped conv3d + SiLU
// xc channel-major: xc[(b*16+co)*4096 + l]
__global__ void k_conv(const float* __restrict__ xz, const float* __restrict__ conv_w,
                       const float* __restrict__ conv_b, float* __restrict__ xc) {
    int t = threadIdx.x;
    int tok = blockIdx.x * 256 + t;
    int co = blockIdx.y;
    int b = tok >> 12, l = tok & 4095;
    int d = l >> 8, h = (l >> 4) & 15, w = l & 15;
    float acc = conv_b[co];
    const float* wr = conv_w + co * 16 * 27;
    for (int i = 0; i < 3; i++) {
        int zd = d + i - 1; if ((unsigned)zd > 15u) continue;
        for (int j = 0; j < 3; j++) {
            int zh = h + j - 1; if ((unsigned)zh > 15u) continue;
            for (int k = 0; k < 3; k++) {
                int zw = w + k - 1; if ((unsigned)zw > 15u) continue;
                int ntok = (b << 12) + (zd << 8) + (zh << 4) + zw;
                const float* xr = xz + ntok * 512 + co * 16;
                int widx = (i * 3 + j) * 3 + k;
#pragma unroll
                for (int q = 0; q < 16; q++)
                    acc += xr[q] * wr[q * 27 + widx];
            }
        }
    }
    acc = acc / (1.f + __expf(-acc));  // SiLU
    xc[(b * 16 + co) * 4096 + l] = acc;
}

// ---------------------------------------------------------------- x_dbl = x_proj_w @ xs
// xs gathered from xc on the fly (unfold). 6 output channels per block (grid.y=8).
// Channels 0..13 (dts) -> dts[b][14][L]; channels 14..45 (B,C) -> bc[b][l][32].
__global__ void k_xdbl(const float* __restrict__ xc, const float* __restrict__ x_proj_w,
                       float* __restrict__ dts, float* __restrict__ bc) {
    int t = threadIdx.x;
    int tok = blockIdx.x * 256 + t;
    int cbase = blockIdx.y * 6;
    int ncs = (cbase + 6 <= 46) ? 6 : (46 - cbase);
    int b = tok >> 12, l = tok & 4095;
    int d0 = l >> 8, h0 = (l >> 4) & 15, w0 = l & 15;
    int nbo[27];
#pragma unroll
    for (int t27 = 0; t27 < 27; t27++) {
        int di = t27 / 9 - 1, dj = (t27 / 3) % 3 - 1, dk = t27 % 3 - 1;
        int zd = d0 + di, zh = h0 + dj, zw = w0 + dk;
        nbo[t27] = ((unsigned)zd > 15u || (unsigned)zh > 15u || (unsigned)zw > 15u)
                   ? -1 : ((zd << 8) + (zh << 4) + zw);
    }
    const float* xcb = xc + b * 16 * 4096;
    float acc[6];
#pragma unroll
    for (int c = 0; c < 6; c++) acc[c] = 0.f;
    for (int ch = 0; ch < 16; ch++) {
        const float* xr = xcb + ch * 4096;
#pragma unroll
        for (int t27 = 0; t27 < 27; t27++) {
            int o = nbo[t27];
            float v = (o >= 0) ? xr[o] : 0.f;
            int didx = ch * 27 + t27;
#pragma unroll
            for (int c = 0; c < 6; c++) {
                if (c < ncs)
                    acc[c] += v * x_proj_w[(cbase + c) * 432 + didx];
            }
        }
    }
    for (int c = 0; c < ncs; c++) {
        int ch = cbase + c;
        if (ch < 14)
            dts[(b * 14 + ch) * 4096 + l] = acc[c];
        else
            bc[((b << 12) + l) * 32 + (ch - 14)] = acc[c];
    }
}

// ---------------------------------------------------------------- delta = softplus(dt_w @ dts + dt_b)
// 16 dd-channels per block (grid.y = 27)
__global__ void k_delta(const float* __restrict__ dts, const float* __restrict__ dt_w,
                        const float* __restrict__ dt_b, float* __restrict__ delta) {
    int t = threadIdx.x;
    int tok = blockIdx.x * 256 + t;
    int ddbase = blockIdx.y * 16;
    int b = tok >> 12, l = tok & 4095;
    const float* xr = dts + b * 14 * 4096;
    float xv[14];
#pragma unroll
    for (int r = 0; r < 14; r++) xv[r] = xr[r * 4096 + l];
#pragma unroll
    for (int dd2 = 0; dd2 < 16; dd2++) {
        int dd = ddbase + dd2;
        float s = dt_b[dd];
#pragma unroll
        for (int r = 0; r < 14; r++) s += xv[r] * dt_w[dd * 14 + r];
        s = (s > 15.f) ? s : log1pf(__expf(s));
        delta[(b * 432 + dd) * 4096 + l] = s;
    }
}

// ---------------------------------------------------------------- selective scan
// One block per (b, d-channel). Thread t owns l in [t*16, t*16+16) with all
// 16 states in registers. Chunk transforms scanned via wave shfl + tiny LDS.
__global__ __launch_bounds__(256) void k_scan(
        const float* __restrict__ xc, const float* __restrict__ delta,
        const float* __restrict__ bc, const float* __restrict__ A_logs,
        const float* __restrict__ Ds, float* __restrict__ y) {
    int bd = blockIdx.x;
    int b = bd / 432, dch = bd % 432;
    int t = threadIdx.x;
    int lane = t & 63, wv = t >> 6;
    int l0 = t * 16;

    float A[16];
#pragma unroll
    for (int n = 0; n < 16; n++) A[n] = -__expf(A_logs[dch * 16 + n]);
    float Dskip = Ds[dch];

    int cch = dch / 27, t27 = dch % 27;
    int di = t27 / 9 - 1, dj = (t27 / 3) % 3 - 1, dk = t27 % 3 - 1;
    const float* xcb = xc + (b * 16 + cch) * 4096;
    const float* dl  = delta + (b * 432 + dch) * 4096 + l0;
    const float* bcb = bc + (size_t)((b << 12) + l0) * 32;

    // thread chunk = one w-row: fixed (d0,h0) = (t>>4, t&15), w = 0..15
    int zd = (t >> 4) + di, zh = (t & 15) + dj;
    bool rowok = ((unsigned)zd <= 15u) && ((unsigned)zh <= 15u);
    const float* xr = xcb + (zd << 8) + (zh << 4);

    float dtv[16], uv[16];
#pragma unroll
    for (int i = 0; i < 16; i++) dtv[i] = dl[i];
#pragma unroll
    for (int i = 0; i < 16; i++) {
        int zw = i + dk;
        uv[i] = (rowok && (unsigned)zw <= 15u) ? xr[zw] : 0.f;
    }

    // ---- pass 1: chunk transform (Ap, Bp) per state
    float Ap[16], Bp[16];
#pragma unroll
    for (int n = 0; n < 16; n++) { Ap[n] = 1.f; Bp[n] = 0.f; }
#pragma unroll 2
    for (int i = 0; i < 16; i++) {
        float dt = dtv[i], dtu = dt * uv[i];
        const float* bl = bcb + i * 32;
#pragma unroll
        for (int n = 0; n < 16; n++) {
            float a = __expf(dt * A[n]);
            Bp[n] = a * Bp[n] + dtu * bl[n];
            Ap[n] *= a;
        }
    }

    // ---- wave-level inclusive scan (Hillis-Steele over 64 lanes)
#pragma unroll
    for (int s = 1; s < 64; s <<= 1) {
#pragma unroll
        for (int n = 0; n < 16; n++) {
            float pa = __shfl_up(Ap[n], s, 64);
            float pb = __shfl_up(Bp[n], s, 64);
            if (lane >= s) {
                Bp[n] = Ap[n] * pb + Bp[n];   // combine(earlier=(pa,pb), later)
                Ap[n] *= pa;
            }
        }
    }

    // ---- cross-wave prefix via tiny LDS
    __shared__ float waggA[4][16], waggB[4][16];
    if (lane == 63) {
#pragma unroll
        for (int n = 0; n < 16; n++) { waggA[wv][n] = Ap[n]; waggB[wv][n] = Bp[n]; }
    }
    __syncthreads();

    float h[16];
#pragma unroll
    for (int n = 0; n < 16; n++) {
        float exA = __shfl_up(Ap[n], 1, 64);
        float exB = __shfl_up(Bp[n], 1, 64);
        if (lane == 0) { exA = 1.f; exB = 0.f; }
        float WB = 0.f;
        for (int ww = 0; ww < wv; ww++)
            WB = waggA[ww][n] * WB + waggB[ww][n];
        h[n] = exA * WB + exB;     // incoming state for this chunk
    }

    // ---- pass 2: rescan with incoming state, in-thread C-dot
    float* yo = y + (size_t)(b * 432 + dch) * 4096 + l0;
#pragma unroll 2
    for (int i = 0; i < 16; i++) {
        float dt = dtv[i], uu = uv[i], dtu = dt * uu;
        const float* bl = bcb + i * 32;
        float ys = 0.f;
#pragma unroll
        for (int n = 0; n < 16; n++) {
            float a = __expf(dt * A[n]);
            h[n] = a * h[n] + dtu * bl[n];
            ys += h[n] * bl[16 + n];
        }
        yo[i] = ys + Dskip * uu;
    }
}

// ---------------------------------------------------------------- fold GEMM + LN + gate + out GEMM
// 16 tokens per block.
__global__ void k_tail(const float* __restrict__ y, const float* __restrict__ xz,
                       const float* __restrict__ wf_t, const float* __restrict__ ln_g,
                       const float* __restrict__ ln_b, const float* __restrict__ wo_t,
                       float* __restrict__ out) {
    int t = threadIdx.x;
    int tokbase = blockIdx.x * 16;
    int b = tokbase >> 12, lbase = tokbase & 4095;
    __shared__ float ys[432][16];
    __shared__ float vs[256][17];
    __shared__ float mu_s[16], rs_s[16];

    for (int idx = t; idx < 432 * 16; idx += 256) {
        int d = idx >> 4, tk = idx & 15;
        ys[d][tk] = y[(b * 432 + d) * 4096 + lbase + tk];
    }
    __syncthreads();

    float acc[16];
#pragma unroll
    for (int k = 0; k < 16; k++) acc[k] = 0.f;
    for (int d = 0; d < 432; d++) {
        float w = wf_t[d * 256 + t];
#pragma unroll
        for (int k = 0; k < 16; k++) acc[k] += w * ys[d][k];
    }
#pragma unroll
    for (int k = 0; k < 16; k++) vs[t][k] = acc[k];
    __syncthreads();

    {
        int tk = t >> 4, sub = t & 15;
        float s = 0.f, s2 = 0.f;
        for (int m = 0; m < 16; m++) {
            float v = vs[sub * 16 + m][tk];
            s += v; s2 += v * v;
        }
        s  += __shfl_xor(s, 1, 64);  s2 += __shfl_xor(s2, 1, 64);
        s  += __shfl_xor(s, 2, 64);  s2 += __shfl_xor(s2, 2, 64);
        s  += __shfl_xor(s, 4, 64);  s2 += __shfl_xor(s2, 4, 64);
        s  += __shfl_xor(s, 8, 64);  s2 += __shfl_xor(s2, 8, 64);
        if (sub == 0) {
            float mu = s * (1.f / 256.f);
            float var = s2 * (1.f / 256.f) - mu * mu;
            mu_s[tk] = mu;
            rs_s[tk] = rsqrtf(var + 1e-5f);
        }
    }
    __syncthreads();

    float g = ln_g[t], be = ln_b[t];
#pragma unroll
    for (int k = 0; k < 16; k++) {
        float zv = xz[(tokbase + k) * 512 + 256 + t];
        float sz = zv / (1.f + __expf(-zv));  // SiLU(z)
        vs[t][k] = ((acc[k] - mu_s[k]) * rs_s[k] * g + be) * sz;
    }
    __syncthreads();

    float oacc[8];
#pragma unroll
    for (int k = 0; k < 8; k++) oacc[k] = 0.f;
    int o = t & 127, kh = (t >> 7) * 8;
    for (int i = 0; i < 256; i++) {
        float w = wo_t[i * 128 + o];
#pragma unroll
        for (int k = 0; k < 8; k++) oacc[k] += w * vs[i][kh + k];
    }
#pragma unroll
    for (int k = 0; k < 8; k++)
        out[(tokbase + kh + k) * 128 + o] = oacc[k];
}

// ---------------------------------------------------------------- launch
extern "C" void kernel_launch(void* const* d_in, const int* in_sizes, int n_in,
                              void* d_out, int out_size, void* d_ws, size_t ws_size,
                              hipStream_t stream) {
    const float* x        = (const float*)d_in[0];
    const float* w_in     = (const float*)d_in[1];
    const float* conv_w   = (const float*)d_in[2];
    const float* conv_b   = (const float*)d_in[3];
    const float* x_proj_w = (const float*)d_in[4];
    const float* dt_w     = (const float*)d_in[5];
    const float* dt_b     = (const float*)d_in[6];
    const float* A_logs   = (const float*)d_in[7];
    const float* Ds       = (const float*)d_in[8];
    const float* w_fold   = (const float*)d_in[9];
    const float* ln_g     = (const float*)d_in[10];
    const float* ln_b     = (const float*)d_in[11];
    const float* w_out    = (const float*)d_in[12];
    float* out = (float*)d_out;

    float* ws    = (float*)d_ws;
    float* xz    = ws;                    // NTOK*512      = 4,194,304
    float* xc    = xz    + 4194304;       // B*16*L        =   131,072
    float* dts   = xc    + 131072;        // B*14*L        =   114,688
    float* bcbuf = dts   + 114688;        // B*L*32        =   262,144
    float* delta = bcbuf + 262144;        // B*432*L       = 3,538,944
    float* ybuf  = delta + 3538944;       // B*432*L       = 3,538,944
    float* wint  = ybuf  + 3538944;       // 512*128       =    65,536
    float* wft   = wint  + 65536;         // 432*256       =   110,592
    float* wot   = wft   + 110592;        // 256*128       =    32,768

    k_transpose<<<dim3((512 * 128 + 255) / 256), dim3(256), 0, stream>>>(w_in, wint, 512, 128);
    k_transpose<<<dim3((256 * 432 + 255) / 256), dim3(256), 0, stream>>>(w_fold, wft, 256, 432);
    k_transpose<<<dim3((128 * 256 + 255) / 256), dim3(256), 0, stream>>>(w_out, wot, 128, 256);

    k_inproj<<<dim3(NTOK / 16), dim3(256), 0, stream>>>(x, wint, xz);
    k_conv<<<dim3(NTOK / 256, CCONV), dim3(256), 0, stream>>>(xz, conv_w, conv_b, xc);
    k_xdbl<<<dim3(NTOK / 256, 8), dim3(256), 0, stream>>>(xc, x_proj_w, dts, bcbuf);
    k_delta<<<dim3(NTOK / 256, 27), dim3(256), 0, stream>>>(dts, dt_w, dt_b, delta);
    k_scan<<<dim3(BATCH * DSEQ), dim3(256), 0, stream>>>(xc, delta, bcbuf, A_logs, Ds, ybuf);
    k_tail<<<dim3(NTOK / 16), dim3(256), 0, stream>>>(ybuf, xz, wft, ln_g, ln_b, wot, out);
}

// Round 3
// 259.681 us; speedup vs baseline: 3.7947x; 1.5020x over previous
//
#include <hip/hip_runtime.h>
#include <hip/hip_bf16.h>

// Problem constants
#define DM     128
#define DSTATE 16
#define DINNER 256
#define CCONV  16
#define NEIGH  27
#define DSEQ   432   // CCONV * NEIGH
#define DTRANK 14
#define LVOL   4096  // 16*16*16
#define BATCH  2
#define NTOK   8192  // BATCH * LVOL

// ---------------------------------------------------------------- transposes
__global__ void k_transpose(const float* __restrict__ src, float* __restrict__ dst,
                            int rows, int cols) {
    int i = blockIdx.x * 256 + threadIdx.x;
    if (i < rows * cols) {
        int r = i / cols, c = i - r * cols;
        dst[c * rows + r] = src[i];
    }
}

// ---------------------------------------------------------------- in-proj GEMM
// xp -> channel-major xpt[(b*256+c)*4096 + l]; z -> token-major zbuf[tok*256 + c]
__global__ void k_inproj(const float* __restrict__ x, const float* __restrict__ w_in_t,
                         float* __restrict__ xpt, float* __restrict__ zbuf) {
    int t = threadIdx.x;
    int tokbase = blockIdx.x * 16;
    int b = tokbase >> 12, lb = tokbase & 4095;
    __shared__ float xs_[16][128];
    for (int idx = t; idx < 2048; idx += 256)
        xs_[idx >> 7][idx & 127] = x[tokbase * 128 + idx];
    __syncthreads();
    float a0[16], a1[16];
#pragma unroll
    for (int k = 0; k < 16; k++) { a0[k] = 0.f; a1[k] = 0.f; }
    for (int j = 0; j < 128; j++) {
        float w0 = w_in_t[j * 512 + t];
        float w1 = w_in_t[j * 512 + t + 256];
#pragma unroll
        for (int k = 0; k < 16; k++) {
            float xv = xs_[k][j];
            a0[k] += xv * w0;
            a1[k] += xv * w1;
        }
    }
    float* xr = xpt + (size_t)(b * 256 + t) * 4096 + lb;
#pragma unroll
    for (int k = 0; k < 16; k++) xr[k] = a0[k];
#pragma unroll
    for (int k = 0; k < 16; k++) zbuf[(tokbase + k) * 256 + t] = a1[k];
}

// ---------------------------------------------------------------- grouped conv3d + SiLU
// one output channel per block (grid.y = 16); coalesced channel-major reads
__global__ void k_conv(const float* __restrict__ xpt, const float* __restrict__ conv_w,
                       const float* __restrict__ conv_b, float* __restrict__ xc) {
    int t = threadIdx.x;
    int tok = blockIdx.x * 256 + t;
    int co = blockIdx.y;
    int b = tok >> 12, l = tok & 4095;
    int d0 = l >> 8, h0 = (l >> 4) & 15, w0 = l & 15;
    __shared__ float wl[432];
    for (int i = t; i < 432; i += 256) wl[i] = conv_w[co * 432 + i];  // [q][27]
    __syncthreads();
    int nbo[27];
#pragma unroll
    for (int t27 = 0; t27 < 27; t27++) {
        int di = t27 / 9 - 1, dj = (t27 / 3) % 3 - 1, dk = t27 % 3 - 1;
        int zd = d0 + di, zh = h0 + dj, zw = w0 + dk;
        nbo[t27] = ((unsigned)zd > 15u || (unsigned)zh > 15u || (unsigned)zw > 15u)
                   ? -1 : ((zd << 8) + (zh << 4) + zw);
    }
    const float* xb = xpt + (size_t)(b * 256 + co * 16) * 4096;
    float acc0 = conv_b[co], acc1 = 0.f;
    for (int t27 = 0; t27 < 27; t27++) {
        int o = nbo[t27];
        if (o >= 0) {
#pragma unroll
            for (int q = 0; q < 16; q += 2) {
                acc0 += xb[q * 4096 + o]       * wl[q * 27 + t27];
                acc1 += xb[(q + 1) * 4096 + o] * wl[(q + 1) * 27 + t27];
            }
        }
    }
    float acc = acc0 + acc1;
    acc = acc / (1.f + __expf(-acc));  // SiLU
    xc[(b * 16 + co) * 4096 + l] = acc;
}

// ---------------------------------------------------------------- x_dbl = x_proj_w @ unfold(xc)
// one output channel per block (grid.y = 46); weights in LDS
__global__ void k_xdbl(const float* __restrict__ xc, const float* __restrict__ x_proj_w,
                       float* __restrict__ dts, float* __restrict__ bc) {
    int t = threadIdx.x;
    int tok = blockIdx.x * 256 + t;
    int c = blockIdx.y;  // 0..45
    int b = tok >> 12, l = tok & 4095;
    int d0 = l >> 8, h0 = (l >> 4) & 15, w0 = l & 15;
    __shared__ float wl[432];
    for (int i = t; i < 432; i += 256) wl[i] = x_proj_w[c * 432 + i];  // [ch][27]
    __syncthreads();
    int nbo[27];
#pragma unroll
    for (int t27 = 0; t27 < 27; t27++) {
        int di = t27 / 9 - 1, dj = (t27 / 3) % 3 - 1, dk = t27 % 3 - 1;
        int zd = d0 + di, zh = h0 + dj, zw = w0 + dk;
        nbo[t27] = ((unsigned)zd > 15u || (unsigned)zh > 15u || (unsigned)zw > 15u)
                   ? -1 : ((zd << 8) + (zh << 4) + zw);
    }
    const float* xcb = xc + b * 16 * 4096;
    float acc0 = 0.f, acc1 = 0.f;
    for (int t27 = 0; t27 < 27; t27++) {
        int o = nbo[t27];
        if (o >= 0) {
#pragma unroll
            for (int ch = 0; ch < 16; ch += 2) {
                acc0 += xcb[ch * 4096 + o]       * wl[ch * 27 + t27];
                acc1 += xcb[(ch + 1) * 4096 + o] * wl[(ch + 1) * 27 + t27];
            }
        }
    }
    float acc = acc0 + acc1;
    if (c < 14)
        dts[(b * 14 + c) * 4096 + l] = acc;
    else
        bc[(size_t)((b << 12) + l) * 32 + (c - 14)] = acc;
}

// ---------------------------------------------------------------- delta = softplus(dt_w @ dts + dt_b)
__global__ void k_delta(const float* __restrict__ dts, const float* __restrict__ dt_w,
                        const float* __restrict__ dt_b, float* __restrict__ delta) {
    int t = threadIdx.x;
    int tok = blockIdx.x * 256 + t;
    int ddbase = blockIdx.y * 16;
    int b = tok >> 12, l = tok & 4095;
    const float* xr = dts + b * 14 * 4096;
    float xv[14];
#pragma unroll
    for (int r = 0; r < 14; r++) xv[r] = xr[r * 4096 + l];
#pragma unroll
    for (int dd2 = 0; dd2 < 16; dd2++) {
        int dd = ddbase + dd2;
        float s = dt_b[dd];
#pragma unroll
        for (int r = 0; r < 14; r++) s += xv[r] * dt_w[dd * 14 + r];
        s = (s > 15.f) ? s : log1pf(__expf(s));
        delta[(b * 432 + dd) * 4096 + l] = s;
    }
}

// ---------------------------------------------------------------- selective scan
// One block per (b, d-channel). Thread t owns l in [t*16, t*16+16) with all
// 16 states in registers. Chunk transforms scanned via wave shfl + tiny LDS.
__global__ __launch_bounds__(256) void k_scan(
        const float* __restrict__ xc, const float* __restrict__ delta,
        const float* __restrict__ bc, const float* __restrict__ A_logs,
        const float* __restrict__ Ds, float* __restrict__ y) {
    int bd = blockIdx.x;
    int b = bd / 432, dch = bd % 432;
    int t = threadIdx.x;
    int lane = t & 63, wv = t >> 6;
    int l0 = t * 16;

    float A[16];
#pragma unroll
    for (int n = 0; n < 16; n++) A[n] = -__expf(A_logs[dch * 16 + n]);
    float Dskip = Ds[dch];

    int cch = dch / 27, t27 = dch % 27;
    int di = t27 / 9 - 1, dj = (t27 / 3) % 3 - 1, dk = t27 % 3 - 1;
    const float* xcb = xc + (b * 16 + cch) * 4096;
    const float* dl  = delta + (b * 432 + dch) * 4096 + l0;
    const float* bcb = bc + (size_t)((b << 12) + l0) * 32;

    // thread chunk = one w-row: fixed (d0,h0) = (t>>4, t&15), w = 0..15
    int zd = (t >> 4) + di, zh = (t & 15) + dj;
    bool rowok = ((unsigned)zd <= 15u) && ((unsigned)zh <= 15u);
    const float* xr = xcb + (zd << 8) + (zh << 4);

    float dtv[16], uv[16];
#pragma unroll
    for (int i = 0; i < 16; i++) dtv[i] = dl[i];
#pragma unroll
    for (int i = 0; i < 16; i++) {
        int zw = i + dk;
        uv[i] = (rowok && (unsigned)zw <= 15u) ? xr[zw] : 0.f;
    }

    // ---- pass 1: chunk transform (Ap, Bp) per state
    float Ap[16], Bp[16];
#pragma unroll
    for (int n = 0; n < 16; n++) { Ap[n] = 1.f; Bp[n] = 0.f; }
#pragma unroll 2
    for (int i = 0; i < 16; i++) {
        float dt = dtv[i], dtu = dt * uv[i];
        const float* bl = bcb + i * 32;
#pragma unroll
        for (int n = 0; n < 16; n++) {
            float a = __expf(dt * A[n]);
            Bp[n] = a * Bp[n] + dtu * bl[n];
            Ap[n] *= a;
        }
    }

    // ---- wave-level inclusive scan (Hillis-Steele over 64 lanes)
#pragma unroll
    for (int s = 1; s < 64; s <<= 1) {
#pragma unroll
        for (int n = 0; n < 16; n++) {
            float pa = __shfl_up(Ap[n], s, 64);
            float pb = __shfl_up(Bp[n], s, 64);
            if (lane >= s) {
                Bp[n] = Ap[n] * pb + Bp[n];   // combine(earlier=(pa,pb), later)
                Ap[n] *= pa;
            }
        }
    }

    // ---- cross-wave prefix via tiny LDS
    __shared__ float waggA[4][16], waggB[4][16];
    if (lane == 63) {
#pragma unroll
        for (int n = 0; n < 16; n++) { waggA[wv][n] = Ap[n]; waggB[wv][n] = Bp[n]; }
    }
    __syncthreads();

    float h[16];
#pragma unroll
    for (int n = 0; n < 16; n++) {
        float exA = __shfl_up(Ap[n], 1, 64);
        float exB = __shfl_up(Bp[n], 1, 64);
        if (lane == 0) { exA = 1.f; exB = 0.f; }
        float WB = 0.f;
        for (int ww = 0; ww < wv; ww++)
            WB = waggA[ww][n] * WB + waggB[ww][n];
        h[n] = exA * WB + exB;     // incoming state for this chunk
    }

    // ---- pass 2: rescan with incoming state, in-thread C-dot
    float* yo = y + (size_t)(b * 432 + dch) * 4096 + l0;
#pragma unroll 2
    for (int i = 0; i < 16; i++) {
        float dt = dtv[i], uu = uv[i], dtu = dt * uu;
        const float* bl = bcb + i * 32;
        float ys = 0.f;
#pragma unroll
        for (int n = 0; n < 16; n++) {
            float a = __expf(dt * A[n]);
            h[n] = a * h[n] + dtu * bl[n];
            ys += h[n] * bl[16 + n];
        }
        yo[i] = ys + Dskip * uu;
    }
}

// ---------------------------------------------------------------- fold GEMM + LN + gate + out GEMM
__global__ void k_tail(const float* __restrict__ y, const float* __restrict__ zbuf,
                       const float* __restrict__ wf_t, const float* __restrict__ ln_g,
                       const float* __restrict__ ln_b, const float* __restrict__ wo_t,
                       float* __restrict__ out) {
    int t = threadIdx.x;
    int tokbase = blockIdx.x * 16;
    int b = tokbase >> 12, lbase = tokbase & 4095;
    __shared__ float ys[432][16];
    __shared__ float vs[256][17];
    __shared__ float mu_s[16], rs_s[16];

    for (int idx = t; idx < 432 * 16; idx += 256) {
        int d = idx >> 4, tk = idx & 15;
        ys[d][tk] = y[(b * 432 + d) * 4096 + lbase + tk];
    }
    __syncthreads();

    float acc[16];
#pragma unroll
    for (int k = 0; k < 16; k++) acc[k] = 0.f;
    for (int d = 0; d < 432; d++) {
        float w = wf_t[d * 256 + t];
#pragma unroll
        for (int k = 0; k < 16; k++) acc[k] += w * ys[d][k];
    }
#pragma unroll
    for (int k = 0; k < 16; k++) vs[t][k] = acc[k];
    __syncthreads();

    {
        int tk = t >> 4, sub = t & 15;
        float s = 0.f, s2 = 0.f;
        for (int m = 0; m < 16; m++) {
            float v = vs[sub * 16 + m][tk];
            s += v; s2 += v * v;
        }
        s  += __shfl_xor(s, 1, 64);  s2 += __shfl_xor(s2, 1, 64);
        s  += __shfl_xor(s, 2, 64);  s2 += __shfl_xor(s2, 2, 64);
        s  += __shfl_xor(s, 4, 64);  s2 += __shfl_xor(s2, 4, 64);
        s  += __shfl_xor(s, 8, 64);  s2 += __shfl_xor(s2, 8, 64);
        if (sub == 0) {
            float mu = s * (1.f / 256.f);
            float var = s2 * (1.f / 256.f) - mu * mu;
            mu_s[tk] = mu;
            rs_s[tk] = rsqrtf(var + 1e-5f);
        }
    }
    __syncthreads();

    float g = ln_g[t], be = ln_b[t];
#pragma unroll
    for (int k = 0; k < 16; k++) {
        float zv = zbuf[(tokbase + k) * 256 + t];
        float sz = zv / (1.f + __expf(-zv));  // SiLU(z)
        vs[t][k] = ((acc[k] - mu_s[k]) * rs_s[k] * g + be) * sz;
    }
    __syncthreads();

    float oacc[8];
#pragma unroll
    for (int k = 0; k < 8; k++) oacc[k] = 0.f;
    int o = t & 127, kh = (t >> 7) * 8;
    for (int i = 0; i < 256; i++) {
        float w = wo_t[i * 128 + o];
#pragma unroll
        for (int k = 0; k < 8; k++) oacc[k] += w * vs[i][kh + k];
    }
#pragma unroll
    for (int k = 0; k < 8; k++)
        out[(tokbase + kh + k) * 128 + o] = oacc[k];
}

// ---------------------------------------------------------------- launch
extern "C" void kernel_launch(void* const* d_in, const int* in_sizes, int n_in,
                              void* d_out, int out_size, void* d_ws, size_t ws_size,
                              hipStream_t stream) {
    const float* x        = (const float*)d_in[0];
    const float* w_in     = (const float*)d_in[1];
    const float* conv_w   = (const float*)d_in[2];
    const float* conv_b   = (const float*)d_in[3];
    const float* x_proj_w = (const float*)d_in[4];
    const float* dt_w     = (const float*)d_in[5];
    const float* dt_b     = (const float*)d_in[6];
    const float* A_logs   = (const float*)d_in[7];
    const float* Ds       = (const float*)d_in[8];
    const float* w_fold   = (const float*)d_in[9];
    const float* ln_g     = (const float*)d_in[10];
    const float* ln_b     = (const float*)d_in[11];
    const float* w_out    = (const float*)d_in[12];
    float* out = (float*)d_out;

    float* ws    = (float*)d_ws;
    float* xpt   = ws;                    // B*256*L       = 2,097,152
    float* zbuf  = xpt   + 2097152;       // NTOK*256      = 2,097,152
    float* xc    = zbuf  + 2097152;       // B*16*L        =   131,072
    float* dts   = xc    + 131072;        // B*14*L        =   114,688
    float* bcbuf = dts   + 114688;        // B*L*32        =   262,144
    float* delta = bcbuf + 262144;        // B*432*L       = 3,538,944
    float* ybuf  = delta + 3538944;       // B*432*L       = 3,538,944
    float* wint  = ybuf  + 3538944;       // 512*128       =    65,536
    float* wft   = wint  + 65536;         // 432*256       =   110,592
    float* wot   = wft   + 110592;        // 256*128       =    32,768

    k_transpose<<<dim3((512 * 128 + 255) / 256), dim3(256), 0, stream>>>(w_in, wint, 512, 128);
    k_transpose<<<dim3((256 * 432 + 255) / 256), dim3(256), 0, stream>>>(w_fold, wft, 256, 432);
    k_transpose<<<dim3((128 * 256 + 255) / 256), dim3(256), 0, stream>>>(w_out, wot, 128, 256);

    k_inproj<<<dim3(NTOK / 16), dim3(256), 0, stream>>>(x, wint, xpt, zbuf);
    k_conv<<<dim3(NTOK / 256, CCONV), dim3(256), 0, stream>>>(xpt, conv_w, conv_b, xc);
    k_xdbl<<<dim3(NTOK / 256, 46), dim3(256), 0, stream>>>(xc, x_proj_w, dts, bcbuf);
    k_delta<<<dim3(NTOK / 256, 27), dim3(256), 0, stream>>>(dts, dt_w, dt_b, delta);
    k_scan<<<dim3(BATCH * DSEQ), dim3(256), 0, stream>>>(xc, delta, bcbuf, A_logs, Ds, ybuf);
    k_tail<<<dim3(NTOK / 16), dim3(256), 0, stream>>>(ybuf, zbuf, wft, ln_g, ln_b, wot, out);
}

// Round 4
// 245.714 us; speedup vs baseline: 4.0103x; 1.0568x over previous
//
#include <hip/hip_runtime.h>
#include <hip/hip_bf16.h>

// Problem constants
#define DM     128
#define DSTATE 16
#define DINNER 256
#define CCONV  16
#define NEIGH  27
#define DSEQ   432   // CCONV * NEIGH
#define DTRANK 14
#define LVOL   4096  // 16*16*16
#define BATCH  2
#define NTOK   8192  // BATCH * LVOL

// ---------------------------------------------------------------- transposes
__global__ void k_transpose(const float* __restrict__ src, float* __restrict__ dst,
                            int rows, int cols) {
    int i = blockIdx.x * 256 + threadIdx.x;
    if (i < rows * cols) {
        int r = i / cols, c = i - r * cols;
        dst[c * rows + r] = src[i];
    }
}

// ---------------------------------------------------------------- in-proj GEMM
// xp -> channel-major xpt[(b*256+c)*4096 + l]; z -> token-major zbuf[tok*256 + c]
__global__ void k_inproj(const float* __restrict__ x, const float* __restrict__ w_in_t,
                         float* __restrict__ xpt, float* __restrict__ zbuf) {
    int t = threadIdx.x;
    int tokbase = blockIdx.x * 16;
    int b = tokbase >> 12, lb = tokbase & 4095;
    __shared__ float xs_[16][128];
    for (int idx = t; idx < 2048; idx += 256)
        xs_[idx >> 7][idx & 127] = x[tokbase * 128 + idx];
    __syncthreads();
    float a0[16], a1[16];
#pragma unroll
    for (int k = 0; k < 16; k++) { a0[k] = 0.f; a1[k] = 0.f; }
    for (int j = 0; j < 128; j++) {
        float w0 = w_in_t[j * 512 + t];
        float w1 = w_in_t[j * 512 + t + 256];
#pragma unroll
        for (int k = 0; k < 16; k++) {
            float xv = xs_[k][j];
            a0[k] += xv * w0;
            a1[k] += xv * w1;
        }
    }
    float* xr = xpt + (size_t)(b * 256 + t) * 4096 + lb;
#pragma unroll
    for (int k = 0; k < 16; k++) xr[k] = a0[k];
#pragma unroll
    for (int k = 0; k < 16; k++) zbuf[(tokbase + k) * 256 + t] = a1[k];
}

// ---------------------------------------------------------------- grouped conv3d + SiLU
// writes xc (l-major, for k_xdbl) and xc3 (w-major transpose, for k_scan)
__global__ void k_conv(const float* __restrict__ xpt, const float* __restrict__ conv_w,
                       const float* __restrict__ conv_b, float* __restrict__ xc,
                       float* __restrict__ xc3) {
    int t = threadIdx.x;
    int tok = blockIdx.x * 256 + t;
    int co = blockIdx.y;
    int b = tok >> 12, l = tok & 4095;
    int d0 = l >> 8, h0 = (l >> 4) & 15, w0 = l & 15;
    __shared__ float wl[432];
    for (int i = t; i < 432; i += 256) wl[i] = conv_w[co * 432 + i];  // [q][27]
    __syncthreads();
    int nbo[27];
#pragma unroll
    for (int t27 = 0; t27 < 27; t27++) {
        int di = t27 / 9 - 1, dj = (t27 / 3) % 3 - 1, dk = t27 % 3 - 1;
        int zd = d0 + di, zh = h0 + dj, zw = w0 + dk;
        nbo[t27] = ((unsigned)zd > 15u || (unsigned)zh > 15u || (unsigned)zw > 15u)
                   ? -1 : ((zd << 8) + (zh << 4) + zw);
    }
    const float* xb = xpt + (size_t)(b * 256 + co * 16) * 4096;
    float acc0 = conv_b[co], acc1 = 0.f;
    for (int t27 = 0; t27 < 27; t27++) {
        int o = nbo[t27];
        if (o >= 0) {
#pragma unroll
            for (int q = 0; q < 16; q += 2) {
                acc0 += xb[q * 4096 + o]       * wl[q * 27 + t27];
                acc1 += xb[(q + 1) * 4096 + o] * wl[(q + 1) * 27 + t27];
            }
        }
    }
    float acc = acc0 + acc1;
    acc = acc / (1.f + __expf(-acc));  // SiLU
    xc[(b * 16 + co) * 4096 + l] = acc;
    // w-major transpose: [b][co][w][d*16+h]
    xc3[((size_t)(b * 16 + co) * 16 + w0) * 256 + (l >> 4)] = acc;
}

// ---------------------------------------------------------------- x_dbl = x_proj_w @ unfold(xc)
// one output channel per block (grid.y = 46); weights in LDS
// c<14 -> dts[b][c][l];  c>=14 -> bc3[b][c-14][l&7][l>>3]
__global__ void k_xdbl(const float* __restrict__ xc, const float* __restrict__ x_proj_w,
                       float* __restrict__ dts, float* __restrict__ bc3) {
    int t = threadIdx.x;
    int tok = blockIdx.x * 256 + t;
    int c = blockIdx.y;  // 0..45
    int b = tok >> 12, l = tok & 4095;
    int d0 = l >> 8, h0 = (l >> 4) & 15, w0 = l & 15;
    __shared__ float wl[432];
    for (int i = t; i < 432; i += 256) wl[i] = x_proj_w[c * 432 + i];  // [ch][27]
    __syncthreads();
    int nbo[27];
#pragma unroll
    for (int t27 = 0; t27 < 27; t27++) {
        int di = t27 / 9 - 1, dj = (t27 / 3) % 3 - 1, dk = t27 % 3 - 1;
        int zd = d0 + di, zh = h0 + dj, zw = w0 + dk;
        nbo[t27] = ((unsigned)zd > 15u || (unsigned)zh > 15u || (unsigned)zw > 15u)
                   ? -1 : ((zd << 8) + (zh << 4) + zw);
    }
    const float* xcb = xc + b * 16 * 4096;
    float acc0 = 0.f, acc1 = 0.f;
    for (int t27 = 0; t27 < 27; t27++) {
        int o = nbo[t27];
        if (o >= 0) {
#pragma unroll
            for (int ch = 0; ch < 16; ch += 2) {
                acc0 += xcb[ch * 4096 + o]       * wl[ch * 27 + t27];
                acc1 += xcb[(ch + 1) * 4096 + o] * wl[(ch + 1) * 27 + t27];
            }
        }
    }
    float acc = acc0 + acc1;
    if (c < 14)
        dts[(b * 14 + c) * 4096 + l] = acc;
    else
        bc3[((size_t)(b * 32 + (c - 14)) * 8 + (l & 7)) * 512 + (l >> 3)] = acc;
}

// ---------------------------------------------------------------- delta = softplus(dt_w @ dts + dt_b)
// writes scan-major delta3[b][dd][l&7][l>>3]
__global__ void k_delta(const float* __restrict__ dts, const float* __restrict__ dt_w,
                        const float* __restrict__ dt_b, float* __restrict__ delta3) {
    int t = threadIdx.x;
    int tok = blockIdx.x * 256 + t;
    int ddbase = blockIdx.y * 16;
    int b = tok >> 12, l = tok & 4095;
    const float* xr = dts + b * 14 * 4096;
    float xv[14];
#pragma unroll
    for (int r = 0; r < 14; r++) xv[r] = xr[r * 4096 + l];
    size_t obase = ((size_t)b * 432) * 8 * 512 + (size_t)(l & 7) * 512 + (l >> 3);
#pragma unroll
    for (int dd2 = 0; dd2 < 16; dd2++) {
        int dd = ddbase + dd2;
        float s = dt_b[dd];
#pragma unroll
        for (int r = 0; r < 14; r++) s += xv[r] * dt_w[dd * 14 + r];
        s = (s > 15.f) ? s : log1pf(__expf(s));
        delta3[obase + (size_t)dd * 8 * 512] = s;
    }
}

// ---------------------------------------------------------------- selective scan
// One block (512 thr) per (b, d-channel). Thread t owns l in [t*8, t*8+8)
// with all 16 states in registers; all loads lane-coalesced via *3 layouts.
__global__ __launch_bounds__(512) void k_scan(
        const float* __restrict__ xc3, const float* __restrict__ delta3,
        const float* __restrict__ bc3, const float* __restrict__ A_logs,
        const float* __restrict__ Ds, float* __restrict__ y) {
    int bd = blockIdx.x;
    int b = bd / 432, dch = bd % 432;
    int t = threadIdx.x;               // 0..511
    int lane = t & 63, wv = t >> 6;    // 8 waves

    float A[16];
#pragma unroll
    for (int n = 0; n < 16; n++) A[n] = -__expf(A_logs[dch * 16 + n]);
    float Dskip = Ds[dch];

    int cch = dch / 27, t27 = dch % 27;
    int di = t27 / 9 - 1, dj = (t27 / 3) % 3 - 1, dk = t27 % 3 - 1;

    // thread chunk: l0 = t*8 -> (d0,h0,w0) = (t>>5, (t>>1)&15, (t&1)*8)
    int d0 = t >> 5, h0 = (t >> 1) & 15, w0 = (t & 1) << 3;
    int zd = d0 + di, zh = h0 + dj;
    bool rowok = ((unsigned)zd <= 15u) && ((unsigned)zh <= 15u);
    const float* xr = xc3 + ((size_t)(b * 16 + cch) * 16) * 256 + (zd << 4) + zh;

    float dtv[8], uv[8];
    const float* dl = delta3 + ((size_t)(b * 432 + dch) * 8) * 512 + t;
#pragma unroll
    for (int i = 0; i < 8; i++) dtv[i] = dl[i * 512];
#pragma unroll
    for (int i = 0; i < 8; i++) {
        int zw = w0 + i + dk;
        uv[i] = (rowok && (unsigned)zw <= 15u) ? xr[zw * 256] : 0.f;
    }

    const float* bcb = bc3 + ((size_t)(b * 32) * 8) * 512 + t;

    // ---- pass 1: chunk transform (Ap, Bp) per state
    float Ap[16], Bp[16];
#pragma unroll
    for (int n = 0; n < 16; n++) { Ap[n] = 1.f; Bp[n] = 0.f; }
#pragma unroll 2
    for (int i = 0; i < 8; i++) {
        float dt = dtv[i], dtu = dt * uv[i];
#pragma unroll
        for (int n = 0; n < 16; n++) {
            float a = __expf(dt * A[n]);
            Bp[n] = a * Bp[n] + dtu * bcb[(size_t)(n * 8 + i) * 512];
            Ap[n] *= a;
        }
    }

    // ---- wave-level inclusive scan (Hillis-Steele over 64 lanes)
#pragma unroll
    for (int s = 1; s < 64; s <<= 1) {
#pragma unroll
        for (int n = 0; n < 16; n++) {
            float pa = __shfl_up(Ap[n], s, 64);
            float pb = __shfl_up(Bp[n], s, 64);
            if (lane >= s) {
                Bp[n] = Ap[n] * pb + Bp[n];   // combine(earlier=(pa,pb), later)
                Ap[n] *= pa;
            }
        }
    }

    // ---- cross-wave prefix via tiny LDS
    __shared__ float waggA[8][16], waggB[8][16];
    if (lane == 63) {
#pragma unroll
        for (int n = 0; n < 16; n++) { waggA[wv][n] = Ap[n]; waggB[wv][n] = Bp[n]; }
    }
    __syncthreads();

    float h[16];
#pragma unroll
    for (int n = 0; n < 16; n++) {
        float exA = __shfl_up(Ap[n], 1, 64);
        float exB = __shfl_up(Bp[n], 1, 64);
        if (lane == 0) { exA = 1.f; exB = 0.f; }
        float WB = 0.f;
        for (int ww = 0; ww < wv; ww++)
            WB = waggA[ww][n] * WB + waggB[ww][n];
        h[n] = exA * WB + exB;     // incoming state for this chunk
    }

    // ---- pass 2: rescan with incoming state, in-thread C-dot
    float* yo = y + (size_t)(b * 432 + dch) * 4096 + t * 8;
#pragma unroll 2
    for (int i = 0; i < 8; i++) {
        float dt = dtv[i], uu = uv[i], dtu = dt * uu;
        float ys = 0.f;
#pragma unroll
        for (int n = 0; n < 16; n++) {
            float a = __expf(dt * A[n]);
            h[n] = a * h[n] + dtu * bcb[(size_t)(n * 8 + i) * 512];
            ys += h[n] * bcb[(size_t)((16 + n) * 8 + i) * 512];
        }
        yo[i] = ys + Dskip * uu;
    }
}

// ---------------------------------------------------------------- fold GEMM + LN + gate + out GEMM
__global__ void k_tail(const float* __restrict__ y, const float* __restrict__ zbuf,
                       const float* __restrict__ wf_t, const float* __restrict__ ln_g,
                       const float* __restrict__ ln_b, const float* __restrict__ wo_t,
                       float* __restrict__ out) {
    int t = threadIdx.x;
    int tokbase = blockIdx.x * 16;
    int b = tokbase >> 12, lbase = tokbase & 4095;
    __shared__ float ys[432][16];
    __shared__ float vs[256][17];
    __shared__ float mu_s[16], rs_s[16];

    for (int idx = t; idx < 432 * 16; idx += 256) {
        int d = idx >> 4, tk = idx & 15;
        ys[d][tk] = y[(b * 432 + d) * 4096 + lbase + tk];
    }
    __syncthreads();

    float acc[16];
#pragma unroll
    for (int k = 0; k < 16; k++) acc[k] = 0.f;
    for (int d = 0; d < 432; d++) {
        float w = wf_t[d * 256 + t];
#pragma unroll
        for (int k = 0; k < 16; k++) acc[k] += w * ys[d][k];
    }
#pragma unroll
    for (int k = 0; k < 16; k++) vs[t][k] = acc[k];
    __syncthreads();

    {
        int tk = t >> 4, sub = t & 15;
        float s = 0.f, s2 = 0.f;
        for (int m = 0; m < 16; m++) {
            float v = vs[sub * 16 + m][tk];
            s += v; s2 += v * v;
        }
        s  += __shfl_xor(s, 1, 64);  s2 += __shfl_xor(s2, 1, 64);
        s  += __shfl_xor(s, 2, 64);  s2 += __shfl_xor(s2, 2, 64);
        s  += __shfl_xor(s, 4, 64);  s2 += __shfl_xor(s2, 4, 64);
        s  += __shfl_xor(s, 8, 64);  s2 += __shfl_xor(s2, 8, 64);
        if (sub == 0) {
            float mu = s * (1.f / 256.f);
            float var = s2 * (1.f / 256.f) - mu * mu;
            mu_s[tk] = mu;
            rs_s[tk] = rsqrtf(var + 1e-5f);
        }
    }
    __syncthreads();

    float g = ln_g[t], be = ln_b[t];
#pragma unroll
    for (int k = 0; k < 16; k++) {
        float zv = zbuf[(tokbase + k) * 256 + t];
        float sz = zv / (1.f + __expf(-zv));  // SiLU(z)
        vs[t][k] = ((acc[k] - mu_s[k]) * rs_s[k] * g + be) * sz;
    }
    __syncthreads();

    float oacc[8];
#pragma unroll
    for (int k = 0; k < 8; k++) oacc[k] = 0.f;
    int o = t & 127, kh = (t >> 7) * 8;
    for (int i = 0; i < 256; i++) {
        float w = wo_t[i * 128 + o];
#pragma unroll
        for (int k = 0; k < 8; k++) oacc[k] += w * vs[i][kh + k];
    }
#pragma unroll
    for (int k = 0; k < 8; k++)
        out[(tokbase + kh + k) * 128 + o] = oacc[k];
}

// ---------------------------------------------------------------- launch
extern "C" void kernel_launch(void* const* d_in, const int* in_sizes, int n_in,
                              void* d_out, int out_size, void* d_ws, size_t ws_size,
                              hipStream_t stream) {
    const float* x        = (const float*)d_in[0];
    const float* w_in     = (const float*)d_in[1];
    const float* conv_w   = (const float*)d_in[2];
    const float* conv_b   = (const float*)d_in[3];
    const float* x_proj_w = (const float*)d_in[4];
    const float* dt_w     = (const float*)d_in[5];
    const float* dt_b     = (const float*)d_in[6];
    const float* A_logs   = (const float*)d_in[7];
    const float* Ds       = (const float*)d_in[8];
    const float* w_fold   = (const float*)d_in[9];
    const float* ln_g     = (const float*)d_in[10];
    const float* ln_b     = (const float*)d_in[11];
    const float* w_out    = (const float*)d_in[12];
    float* out = (float*)d_out;

    float* ws     = (float*)d_ws;
    float* xpt    = ws;                    // B*256*L       = 2,097,152
    float* zbuf   = xpt    + 2097152;      // NTOK*256      = 2,097,152
    float* xc     = zbuf   + 2097152;      // B*16*L        =   131,072
    float* xc3    = xc     + 131072;       // B*16*L        =   131,072
    float* dts    = xc3    + 131072;       // B*14*L        =   114,688
    float* bc3    = dts    + 114688;       // B*32*8*512    =   262,144
    float* delta3 = bc3    + 262144;       // B*432*8*512   = 3,538,944
    float* ybuf   = delta3 + 3538944;      // B*432*L       = 3,538,944
    float* wint   = ybuf   + 3538944;      // 512*128       =    65,536
    float* wft    = wint   + 65536;        // 432*256       =   110,592
    float* wot    = wft    + 110592;       // 256*128       =    32,768

    k_transpose<<<dim3((512 * 128 + 255) / 256), dim3(256), 0, stream>>>(w_in, wint, 512, 128);
    k_transpose<<<dim3((256 * 432 + 255) / 256), dim3(256), 0, stream>>>(w_fold, wft, 256, 432);
    k_transpose<<<dim3((128 * 256 + 255) / 256), dim3(256), 0, stream>>>(w_out, wot, 128, 256);

    k_inproj<<<dim3(NTOK / 16), dim3(256), 0, stream>>>(x, wint, xpt, zbuf);
    k_conv<<<dim3(NTOK / 256, CCONV), dim3(256), 0, stream>>>(xpt, conv_w, conv_b, xc, xc3);
    k_xdbl<<<dim3(NTOK / 256, 46), dim3(256), 0, stream>>>(xc, x_proj_w, dts, bc3);
    k_delta<<<dim3(NTOK / 256, 27), dim3(256), 0, stream>>>(dts, dt_w, dt_b, delta3);
    k_scan<<<dim3(BATCH * DSEQ), dim3(512), 0, stream>>>(xc3, delta3, bc3, A_logs, Ds, ybuf);
    k_tail<<<dim3(NTOK / 16), dim3(256), 0, stream>>>(ybuf, zbuf, wft, ln_g, ln_b, wot, out);
}